// Round 1
// baseline (331.654 us; speedup 1.0000x reference)
//
#include <hip/hip_runtime.h>
#include <stdint.h>

// ---------------------------------------------------------------------------
// SelfAttention: out = softmax((x Wq^T)(x Wk^T)^T / sqrt(E)) (x Wv^T)
// B=4, S=2048, E=1024. All heavy math on bf16 MFMA (fp32 accumulate).
// ---------------------------------------------------------------------------

typedef __attribute__((ext_vector_type(8))) short bf16x8;   // 8 bf16 = 4 VGPRs
typedef __attribute__((ext_vector_type(4))) float f32x4;

__device__ __forceinline__ float bf2f(uint16_t u) {
    return __uint_as_float(((uint32_t)u) << 16);
}
__device__ __forceinline__ uint16_t f2bf(float f) {
    uint32_t u = __float_as_uint(f);
    uint32_t r = u + 0x7FFFu + ((u >> 16) & 1u);   // RNE
    return (uint16_t)(r >> 16);
}

// ---- cast fp32 -> bf16, vectorized x4 -------------------------------------
__global__ __launch_bounds__(256) void cast_f32_bf16(const float* __restrict__ in,
                                                     uint16_t* __restrict__ out,
                                                     int n4) {
    int i = blockIdx.x * 256 + threadIdx.x;
    if (i < n4) {
        float4 v = ((const float4*)in)[i];
        ushort4 o;
        o.x = f2bf(v.x); o.y = f2bf(v.y); o.z = f2bf(v.z); o.w = f2bf(v.w);
        ((ushort4*)out)[i] = o;
    }
}

// ---- bf16 tile transpose: in[rows][cols] -> out[cols][rows], z-batched ----
__global__ __launch_bounds__(256) void transpose_bf16(const uint16_t* __restrict__ in,
                                                      uint16_t* __restrict__ out,
                                                      int rows, int cols) {
    __shared__ uint16_t tile[32][33];
    size_t bo = (size_t)blockIdx.z * rows * cols;
    in += bo; out += bo;
    int bx = blockIdx.x * 32;   // col base
    int by = blockIdx.y * 32;   // row base
    int tx = threadIdx.x, ty = threadIdx.y;   // 32 x 8
    #pragma unroll
    for (int i = ty; i < 32; i += 8)
        tile[i][tx] = in[(size_t)(by + i) * cols + bx + tx];
    __syncthreads();
    #pragma unroll
    for (int i = ty; i < 32; i += 8)
        out[(size_t)(bx + i) * rows + by + tx] = tile[tx][i];
}

// ---- row softmax over 2048 bf16 elements, in place, one block per row -----
__global__ __launch_bounds__(256) void softmax_rows(uint16_t* __restrict__ P) {
    const int n = 2048;
    uint16_t* row = P + (size_t)blockIdx.x * n;
    int tid = threadIdx.x;
    int w = tid >> 6, ln = tid & 63;
    float v[8];
    float m = -3.4e38f;
    #pragma unroll
    for (int i = 0; i < 8; i++) { v[i] = bf2f(row[tid + 256 * i]); m = fmaxf(m, v[i]); }
    #pragma unroll
    for (int o = 32; o >= 1; o >>= 1) m = fmaxf(m, __shfl_down(m, o, 64));
    __shared__ float smax[4], ssum[4];
    if (ln == 0) smax[w] = m;
    __syncthreads();
    m = fmaxf(fmaxf(smax[0], smax[1]), fmaxf(smax[2], smax[3]));
    float s = 0.f;
    #pragma unroll
    for (int i = 0; i < 8; i++) { v[i] = __expf(v[i] - m); s += v[i]; }
    #pragma unroll
    for (int o = 32; o >= 1; o >>= 1) s += __shfl_down(s, o, 64);
    if (ln == 0) ssum[w] = s;
    __syncthreads();
    s = ssum[0] + ssum[1] + ssum[2] + ssum[3];
    float inv = 1.f / s;
    #pragma unroll
    for (int i = 0; i < 8; i++) row[tid + 256 * i] = f2bf(v[i] * inv);
}

// ---- NT GEMM: C[M][N] = alpha * A[M][K] * B[N][K]^T  (bf16 in, OutT out) --
// 128x128 block tile, BK=32, 256 threads = 4 waves, each wave 64x64 via
// 4x4 grid of mfma_f32_16x16x32_bf16. LDS row stride 40 (pad 8) -> 2-way
// bank aliasing only (free). z-batched via element strides.
#define BM 128
#define BN 128
#define BK 32
#define LDSS 40   // elements; 40*2=80 B row stride, 16B-aligned

template <typename OutT>
__global__ __launch_bounds__(256) void gemm_nt(const uint16_t* __restrict__ A,
                                               const uint16_t* __restrict__ B,
                                               OutT* __restrict__ C,
                                               int M, int N, int K, float alpha,
                                               long sA, long sB, long sC) {
    int bz = blockIdx.z;
    A += (long)bz * sA;
    B += (long)bz * sB;
    C += (long)bz * sC;

    __shared__ uint16_t As[BM * LDSS];
    __shared__ uint16_t Bs[BN * LDSS];

    const int tid  = threadIdx.x;
    const int m0   = blockIdx.y * BM;
    const int n0   = blockIdx.x * BN;
    const int wave = tid >> 6;
    const int lane = tid & 63;
    const int quad = lane >> 4;
    const int l16  = lane & 15;
    const int wr   = (wave >> 1) * 64;   // wave row offset in tile
    const int wc   = (wave & 1) * 64;    // wave col offset in tile

    // staging: each thread loads 2x 8-elem vectors per operand per K-step
    const int sr = tid >> 2;            // 0..63
    const int sc = (tid & 3) * 8;       // 0,8,16,24
    const uint16_t* Aptr = A + (long)(m0 + sr) * K + sc;
    const uint16_t* Bptr = B + (long)(n0 + sr) * K + sc;

    f32x4 acc[4][4] = {};

    for (int k0 = 0; k0 < K; k0 += BK) {
        bf16x8 a0 = *(const bf16x8*)(Aptr);
        bf16x8 a1 = *(const bf16x8*)(Aptr + (long)64 * K);
        bf16x8 b0 = *(const bf16x8*)(Bptr);
        bf16x8 b1 = *(const bf16x8*)(Bptr + (long)64 * K);
        Aptr += BK; Bptr += BK;

        __syncthreads();   // previous iteration's compute done
        *(bf16x8*)(&As[sr * LDSS + sc])        = a0;
        *(bf16x8*)(&As[(sr + 64) * LDSS + sc]) = a1;
        *(bf16x8*)(&Bs[sr * LDSS + sc])        = b0;
        *(bf16x8*)(&Bs[(sr + 64) * LDSS + sc]) = b1;
        __syncthreads();

        const int ko = quad * 8;
        bf16x8 af[4], bfr[4];
        #pragma unroll
        for (int i = 0; i < 4; i++)
            af[i] = *(const bf16x8*)(&As[(wr + i * 16 + l16) * LDSS + ko]);
        #pragma unroll
        for (int j = 0; j < 4; j++)
            bfr[j] = *(const bf16x8*)(&Bs[(wc + j * 16 + l16) * LDSS + ko]);
        #pragma unroll
        for (int i = 0; i < 4; i++)
            #pragma unroll
            for (int j = 0; j < 4; j++)
                acc[i][j] = __builtin_amdgcn_mfma_f32_16x16x32_bf16(af[i], bfr[j], acc[i][j], 0, 0, 0);
    }

    // epilogue: C/D layout col = lane&15, row = quad*4 + reg
    #pragma unroll
    for (int i = 0; i < 4; i++) {
        #pragma unroll
        for (int j = 0; j < 4; j++) {
            #pragma unroll
            for (int r = 0; r < 4; r++) {
                int row = m0 + wr + i * 16 + quad * 4 + r;
                int col = n0 + wc + j * 16 + l16;
                float val = acc[i][j][r] * alpha;
                if constexpr (sizeof(OutT) == 2)
                    C[(long)row * N + col] = f2bf(val);
                else
                    C[(long)row * N + col] = val;
            }
        }
    }
}

// ---------------------------------------------------------------------------
extern "C" void kernel_launch(void* const* d_in, const int* in_sizes, int n_in,
                              void* d_out, int out_size, void* d_ws, size_t ws_size,
                              hipStream_t stream) {
    const float* x  = (const float*)d_in[0];
    const float* Wq = (const float*)d_in[1];
    const float* Wk = (const float*)d_in[2];
    const float* Wv = (const float*)d_in[3];
    float* out = (float*)d_out;

    const int Bn = 4, S = 2048, E = 1024;
    const long MS = (long)Bn * S;              // 8192 total rows

    // workspace layout (bf16 buffers), ~118 MB total
    char* ws = (char*)d_ws;
    const size_t SZ_XB = (size_t)MS * E * 2;            // 16 MB
    const size_t SZ_W  = (size_t)E * E * 2;             //  2 MB
    const size_t SZ_P  = (size_t)Bn * S * S * 2;        // 32 MB
    const size_t SZ_VT = (size_t)Bn * E * S * 2;        // 16 MB
    uint16_t* xb  = (uint16_t*)ws;              ws += SZ_XB;
    uint16_t* wqb = (uint16_t*)ws;              ws += SZ_W;
    uint16_t* wkb = (uint16_t*)ws;              ws += SZ_W;
    uint16_t* wvb = (uint16_t*)ws;              ws += SZ_W;
    uint16_t* Qb  = (uint16_t*)ws;              ws += SZ_XB;
    uint16_t* Kb  = (uint16_t*)ws;              ws += SZ_XB;
    uint16_t* Vb  = (uint16_t*)ws;              ws += SZ_XB;
    uint16_t* Pb  = (uint16_t*)ws;              ws += SZ_P;
    uint16_t* Vt  = (uint16_t*)ws;              ws += SZ_VT;

    dim3 blk(256);

    // 1) casts to bf16
    {
        int n4 = (int)(MS * E / 4);
        cast_f32_bf16<<<dim3((n4 + 255) / 256), blk, 0, stream>>>(x, xb, n4);
        int n4w = E * E / 4;
        dim3 gw((n4w + 255) / 256);
        cast_f32_bf16<<<gw, blk, 0, stream>>>(Wq, wqb, n4w);
        cast_f32_bf16<<<gw, blk, 0, stream>>>(Wk, wkb, n4w);
        cast_f32_bf16<<<gw, blk, 0, stream>>>(Wv, wvb, n4w);
    }

    // 2) Q/K/V = xb * W^T   (M=8192, N=1024, K=1024), bf16 out
    {
        dim3 g(E / BN, MS / BM, 1);   // (8, 64)
        gemm_nt<uint16_t><<<g, blk, 0, stream>>>(xb, wqb, Qb, (int)MS, E, E, 1.f, 0, 0, 0);
        gemm_nt<uint16_t><<<g, blk, 0, stream>>>(xb, wkb, Kb, (int)MS, E, E, 1.f, 0, 0, 0);
        gemm_nt<uint16_t><<<g, blk, 0, stream>>>(xb, wvb, Vb, (int)MS, E, E, 1.f, 0, 0, 0);
    }

    // 3) Vt[b][e][k] = V[b][k][e]
    transpose_bf16<<<dim3(E / 32, S / 32, Bn), dim3(32, 8), 0, stream>>>(Vb, Vt, S, E);

    // 4) scores = (Q K^T) / sqrt(E)  per batch, bf16 out
    {
        dim3 g(S / BN, S / BM, Bn);   // (16, 16, 4)
        gemm_nt<uint16_t><<<g, blk, 0, stream>>>(Qb, Kb, Pb, S, S, E, 0.03125f,
                                                 (long)S * E, (long)S * E, (long)S * S);
    }

    // 5) softmax rows in place (4*2048 rows of 2048)
    softmax_rows<<<dim3(Bn * S), blk, 0, stream>>>(Pb);

    // 6) out = P * V = P * Vt^T  (M=2048, N=1024, K=2048 per batch), fp32 out
    {
        dim3 g(E / BN, S / BM, Bn);   // (8, 16, 4)
        gemm_nt<float><<<g, blk, 0, stream>>>(Pb, Vt, out, S, E, S, 1.f,
                                              (long)S * S, (long)E * S, (long)S * E);
    }
}